// Round 18
// baseline (176.817 us; speedup 1.0000x reference)
//
#include <hip/hip_runtime.h>
#include <stdint.h>

#define T_STEPS 100
#define BB 4
#define NN 512
#define KK 10
#define LOG2E 1.4426950408889634

typedef float f4 __attribute__((ext_vector_type(4)));

// ---------------- threefry2x32 (JAX-compatible, 20 rounds) ----------------
__device__ __forceinline__ uint32_t rotl32(uint32_t v, int d) {
  return (v << d) | (v >> (32 - d));
}

__device__ __forceinline__ void tf2x32(uint32_t k0, uint32_t k1,
                                       uint32_t& x0, uint32_t& x1) {
  uint32_t k2 = k0 ^ k1 ^ 0x1BD11BDAu;
  x0 += k0; x1 += k1;
#define TFR(r) { x0 += x1; x1 = rotl32(x1, r); x1 ^= x0; }
  TFR(13) TFR(15) TFR(26) TFR(6)   x0 += k1; x1 += k2 + 1u;
  TFR(17) TFR(29) TFR(16) TFR(24)  x0 += k2; x1 += k0 + 2u;
  TFR(13) TFR(15) TFR(26) TFR(6)   x0 += k0; x1 += k1 + 3u;
  TFR(17) TFR(29) TFR(16) TFR(24)  x0 += k1; x1 += k2 + 4u;
  TFR(13) TFR(15) TFR(26) TFR(6)   x0 += k2; x1 += k0 + 5u;
#undef TFR
}

__device__ __forceinline__ float bits_to_u01(uint32_t bits) {
  return __fsub_rn(__uint_as_float((bits >> 9) | 0x3f800000u), 1.0f);
}

// XLA ErfInv32 (Giles)
__device__ __forceinline__ float erfinv_f32(float x) {
  float w = -logf(__fmul_rn(__fsub_rn(1.0f, x), __fadd_rn(1.0f, x)));
  float p;
  if (w < 5.0f) {
    w = __fsub_rn(w, 2.5f);
    p = 2.81022636e-08f;
    p = __fadd_rn(__fmul_rn(p, w), 3.43273939e-07f);
    p = __fadd_rn(__fmul_rn(p, w), -3.5233877e-06f);
    p = __fadd_rn(__fmul_rn(p, w), -4.39150654e-06f);
    p = __fadd_rn(__fmul_rn(p, w), 0.00021858087f);
    p = __fadd_rn(__fmul_rn(p, w), -0.00125372503f);
    p = __fadd_rn(__fmul_rn(p, w), -0.00417768164f);
    p = __fadd_rn(__fmul_rn(p, w), 0.246640727f);
    p = __fadd_rn(__fmul_rn(p, w), 1.50140941f);
  } else {
    w = __fsub_rn(sqrtf(w), 3.0f);
    p = -0.000200214257f;
    p = __fadd_rn(__fmul_rn(p, w), 0.000100950558f);
    p = __fadd_rn(__fmul_rn(p, w), 0.00134934322f);
    p = __fadd_rn(__fmul_rn(p, w), -0.00367342844f);
    p = __fadd_rn(__fmul_rn(p, w), 0.00573950773f);
    p = __fadd_rn(__fmul_rn(p, w), -0.0076224613f);
    p = __fadd_rn(__fmul_rn(p, w), 0.00943887047f);
    p = __fadd_rn(__fmul_rn(p, w), 1.00167406f);
    p = __fadd_rn(__fmul_rn(p, w), 2.83297682f);
  }
  return __fmul_rn(p, x);
}

// fast sigmoid: 1/(1+exp(-x)) via native exp + native rcp
__device__ __forceinline__ float fast_sigmoid(float x) {
  float e = __expf(-x);
  return __builtin_amdgcn_rcpf(__fadd_rn(1.0f, e));
}

template <int CTRL>
__device__ __forceinline__ float dpp_add(float x) {
  int v = __builtin_amdgcn_update_dpp(0, __float_as_int(x), CTRL, 0xF, 0xF, true);
  return __fadd_rn(x, __int_as_float(v));
}

__device__ __forceinline__ void waitflag(uint32_t* f, uint32_t target) {
  while (__hip_atomic_load(f, __ATOMIC_ACQUIRE, __HIP_MEMORY_SCOPE_AGENT) < target)
    __builtin_amdgcn_s_sleep(2);
}

// ------- Fused kernel: block 0 = chain (prio-3 wave); 1..1616 = ll chunks ---
// ci = bid-1.  ci in [0,16): ll0 (b=ci>>2, jc=ci&3).  ci in [16,1616): llt
// chunk cl=ci-16 -> tb=cl>>2 (ascending t with bid), jc=cl&3.  Producers
// publish chunks with threadfence + device-scope release atomicAdd;
// done[t]==16 -> step t available; done[100]==16 -> ll0 available.
// Chain wave runs at s_setprio(3) so co-resident producer waves fill its
// stall cycles instead of stealing issue slots (T5 mechanism).

#define CH_LOAD(P, T)                                                        \
  {                                                                          \
    _Pragma("unroll")                                                        \
    for (int b = 0; b < 4; b++) {                                            \
      _Pragma("unroll")                                                      \
      for (int k = 0; k < 2; k++)                                            \
        P[b * 2 + k] = lltv[((size_t)(T) * 4 + b) * 128 + k * 64 + g];       \
    }                                                                        \
  }

#define CH_STEP(P, T)                                                        \
  {                                                                          \
    float4 ua = uaccv[T];                                                    \
    f4 tp0 = (P[0] + P[2]) + (P[4] + P[6]);                                  \
    f4 tp1 = (P[1] + P[3]) + (P[5] + P[7]);                                  \
    f4 d0 = tp0 - S0;                                                        \
    f4 d1 = tp1 - S1;                                                        \
    f4 E0, E1;                                                               \
    _Pragma("unroll")                                                        \
    for (int c = 0; c < 4; c++) {                                            \
      E0[c] = fminf(exp2f(d0[c]), 1.0f);                                     \
      E1[c] = fminf(exp2f(d1[c]), 1.0f);                                     \
    }                                                                        \
    f4 Es = E0 + E1;                                                         \
    float ps = __fadd_rn(__fadd_rn(Es[0], Es[1]), __fadd_rn(Es[2], Es[3]));  \
    ps = dpp_add<0xB1>(ps);   /* xor1 */                                     \
    ps = dpp_add<0x4E>(ps);   /* xor2 */                                     \
    ps = dpp_add<0x141>(ps);  /* xor4 (half-mirror) */                       \
    ps = dpp_add<0x140>(ps);  /* xor8 (mirror) */                            \
    ps = __fadd_rn(ps, __int_as_float(__builtin_amdgcn_ds_swizzle(           \
             __float_as_int(ps), 0x401F)));  /* xor16 */                     \
    ps = __fadd_rn(ps, __int_as_float(__builtin_amdgcn_ds_bpermute(          \
             lx32, __float_as_int(ps))));    /* xor32 */                     \
    if (ua.x < ps) { st0 = (T); cur[0] = P[0]; cur[1] = P[1]; }              \
    if (ua.y < ps) { st1 = (T); cur[2] = P[2]; cur[3] = P[3]; }              \
    if (ua.z < ps) { st2 = (T); cur[4] = P[4]; cur[5] = P[5]; }              \
    if (ua.w < ps) { st3 = (T); cur[6] = P[6]; cur[7] = P[7]; }              \
    S0 = (cur[0] + cur[2]) + (cur[4] + cur[6]);                              \
    S1 = (cur[1] + cur[3]) + (cur[5] + cur[7]);                              \
    if (g == 0) {                                                            \
      uint32_t pk = (uint32_t)(st0 + 1) | ((uint32_t)(st1 + 1) << 8) |       \
                    ((uint32_t)(st2 + 1) << 16) | ((uint32_t)(st3 + 1) << 24);\
      spk[T] = pk;                                                           \
    }                                                                        \
  }

__global__ __launch_bounds__(512) void fused_kernel(const float* __restrict__ mu,
                                                    const float* __restrict__ sig,
                                                    const float* __restrict__ pi,
                                                    const float* __restrict__ A0,
                                                    float* __restrict__ pm,
                                                    float* __restrict__ uacc,
                                                    float* __restrict__ llt,
                                                    float* __restrict__ ll0,
                                                    uint32_t* __restrict__ done,
                                                    int* __restrict__ slist,
                                                    float* __restrict__ wlist,
                                                    int* __restrict__ Mv) {
  __shared__ float spm[NN];
  __shared__ float sLc[NN];
  __shared__ double pt[4][128];
  __shared__ uint32_t spk[T_STEPS];
  __shared__ int scnt[BB][101];
  int tid = threadIdx.x;
  int bid = blockIdx.x;

  if (bid > 0) {
    // ---------------- producer: exactly one ll chunk ----------------
    int ci = bid - 1;
    int q = tid >> 7, jj = tid & 127;
    if (ci >= 16) {
      int cl = ci - 16;
      int tb = cl >> 2, jc = cl & 3;
      int t = tb >> 2, b = tb & 3;
      {
        int m = b * NN + tid;
        const float* pp = pi + m * KK;
        float mx = pp[0];
        for (int k = 1; k < KK; k++) mx = fmaxf(mx, pp[k]);
        float e[KK]; float s = 0.0f;
        for (int k = 0; k < KK; k++) { e[k] = expf(__fsub_rn(pp[k], mx)); s = __fadd_rn(s, e[k]); }
        float smv = 0.0f, ssv = 0.0f, eps = 0.0f;
        for (int k = 0; k < KK; k++) {
          float p = e[k] / s;
          smv = __fadd_rn(smv, __fmul_rn(p, mu[m * KK + k]));
          ssv = __fadd_rn(ssv, __fmul_rn(p, sig[m * KK + k]));
          eps = __fadd_rn(eps, pp[k]);
        }
        float ep = fminf(fmaxf(eps, 1e-8f), 1.0f);
        float lep = logf(ep);
        float l1 = logf(__fsub_rn(1.0f, ep));
        sLc[tid] = (float)((double)lep - (double)l1);

        uint32_t kk0 = 0u, kk1 = (uint32_t)t;
        tf2x32(0u, 42u, kk0, kk1);
        uint32_t n0 = 0u, n1 = 0u; tf2x32(kk0, kk1, n0, n1);   // k_noise
        uint32_t y0 = 0u, y1 = (uint32_t)m;
        tf2x32(n0, n1, y0, y1);
        uint32_t bits = y0 ^ y1;
        float u01 = bits_to_u01(bits);
        const float lo = -0.99999994f;
        float u = fmaxf(lo, __fadd_rn(__fmul_rn(u01, 2.0f), lo));
        float z = __fmul_rn(1.41421356237309515f, erfinv_f32(u));
        float pmv = __fadd_rn(smv, __fmul_rn(z, ssv));
        spm[tid] = pmv;
        if (jc == 0) pm[tb * NN + tid] = pmv;
        if (jc == 0 && b == 0 && tid < 4) {
          uint32_t u0 = 0u, u1 = 1u; tf2x32(kk0, kk1, u0, u1); // k_unif
          uint32_t c0 = 0u, c1 = (uint32_t)tid;
          tf2x32(u0, u1, c0, c1);
          uacc[t * 4 + tid] = __fmul_rn(bits_to_u01(c0 ^ c1), 512.0f);
        }
      }
      __syncthreads();
      int j = jc * 128 + jj;
      float pmj = spm[j];
      int i0 = q * 128;
      double acc = 0.0;
      #pragma unroll 8
      for (int i = 0; i < 128; i += 2) {
        float x0 = __fmul_rn(spm[i0 + i], pmj);
        float x1 = __fmul_rn(spm[i0 + i + 1], pmj);
        float t0 = __fmul_rn(fast_sigmoid(x0), sLc[i0 + i]);
        float t1 = __fmul_rn(fast_sigmoid(x1), sLc[i0 + i + 1]);
        acc += (double)__fadd_rn(t0, t1);
      }
      pt[q][jj] = acc;
      __syncthreads();
      if (tid < 128) {
        double a = ((pt[0][jj] + pt[1][jj]) + pt[2][jj]) + pt[3][jj];
        llt[tb * NN + jc * 128 + jj] = (float)(a * LOG2E);
      }
      __syncthreads();
      if (tid == 0) {
        __threadfence();
        __hip_atomic_fetch_add(&done[t], 1u, __ATOMIC_RELEASE,
                               __HIP_MEMORY_SCOPE_AGENT);
      }
    } else {
      int b = ci >> 2, jc = ci & 3;
      {
        int m = b * NN + tid;
        const float* pp = pi + m * KK;
        float eps = 0.0f;
        for (int k = 0; k < KK; k++) eps = __fadd_rn(eps, pp[k]);
        float ep = fminf(fmaxf(eps, 1e-8f), 1.0f);
        float lep = logf(ep);
        float l1 = logf(__fsub_rn(1.0f, ep));
        sLc[tid] = (float)((double)lep - (double)l1);
      }
      __syncthreads();
      int j = jc * 128 + jj;
      int i0 = q * 128;
      double acc = 0.0;
      #pragma unroll 4
      for (int i = 0; i < 128; i++) {
        acc += (double)A0[(size_t)(i0 + i) * NN + j] * (double)sLc[i0 + i];
      }
      pt[q][jj] = acc;
      __syncthreads();
      if (tid < 128) {
        double a = ((pt[0][jj] + pt[1][jj]) + pt[2][jj]) + pt[3][jj];
        ll0[b * NN + jc * 128 + jj] = (float)(a * LOG2E);
      }
      __syncthreads();
      if (tid == 0) {
        __threadfence();
        __hip_atomic_fetch_add(&done[100], 1u, __ATOMIC_RELEASE,
                               __HIP_MEMORY_SCOPE_AGENT);
      }
    }
    return;
  }

  // ---------------- chain block (bid == 0), priority-3 wave ----------------
  if (tid < 64) {
    __builtin_amdgcn_s_setprio(3);   // chain wave outranks producer waves
    int g = tid;
    int lx32 = (g ^ 32) << 2;
    const f4* lltv = (const f4*)llt;
    const f4* ll0v = (const f4*)ll0;
    const float4* uaccv = (const float4*)uacc;

    waitflag(&done[100], 16);  // ll0 ready
    f4 cur[8];
    #pragma unroll
    for (int b = 0; b < 4; b++)
      #pragma unroll
      for (int k = 0; k < 2; k++) cur[b * 2 + k] = ll0v[b * 128 + k * 64 + g];
    f4 S0 = (cur[0] + cur[2]) + (cur[4] + cur[6]);
    f4 S1 = (cur[1] + cur[3]) + (cur[5] + cur[7]);
    int st0 = -1, st1 = -1, st2 = -1, st3 = -1;

    f4 Pa[8], Pb[8], Pc[8];
    waitflag(&done[0], 16); CH_LOAD(Pa, 0)
    waitflag(&done[1], 16); CH_LOAD(Pb, 1)
    waitflag(&done[2], 16); CH_LOAD(Pc, 2)

    for (int t = 0; t < 99; t += 3) {
      CH_STEP(Pa, t)
      if (t + 3 < T_STEPS) { waitflag(&done[t + 3], 16); CH_LOAD(Pa, t + 3) }
      CH_STEP(Pb, t + 1)
      if (t + 4 < T_STEPS) { waitflag(&done[t + 4], 16); CH_LOAD(Pb, t + 4) }
      CH_STEP(Pc, t + 2)
      if (t + 5 < T_STEPS) { waitflag(&done[t + 5], 16); CH_LOAD(Pc, t + 5) }
    }
    CH_STEP(Pa, 99)
    __builtin_amdgcn_s_setprio(0);
  }

  // ---- epilogue: histogram + compacted (state, weight) list ----
  __syncthreads();
  for (int s = tid; s < BB * 101; s += 512) (&scnt[0][0])[s] = 0;
  __syncthreads();
  if (tid < T_STEPS) {
    uint32_t p0 = spk[tid];
    atomicAdd(&scnt[0][p0 & 255], 1);
    atomicAdd(&scnt[1][(p0 >> 8) & 255], 1);
    atomicAdd(&scnt[2][(p0 >> 16) & 255], 1);
    atomicAdd(&scnt[3][p0 >> 24], 1);
  }
  __syncthreads();
  if (tid < 4) {
    int m = 0;
    for (int s = 0; s <= 100; s++) {
      int c = scnt[tid][s];
      if (c) { slist[tid * 104 + m] = s; wlist[tid * 104 + m] = (float)c; m++; }
    }
    Mv[tid] = m;
  }
}

// ---------------- Kernel E: out via compacted state list --------------------
__global__ __launch_bounds__(512) void out_kernel(const float* __restrict__ pm,
                                                  const float* __restrict__ A0,
                                                  const int* __restrict__ slist,
                                                  const float* __restrict__ wlist,
                                                  const int* __restrict__ Mv,
                                                  float* __restrict__ out) {
  int b = blockIdx.x >> 9;
  int i = blockIdx.x & 511;
  int j = threadIdx.x;
  int M = Mv[b];
  float r = 0.0f;
  for (int e = 0; e < M; e++) {
    int s = slist[b * 104 + e];
    float w = wlist[b * 104 + e];
    if (s == 0) {
      r += w * A0[(size_t)i * NN + j];
    } else {
      int t = s - 1;
      float pmi = pm[(size_t)(t * BB + b) * NN + i];
      float pmj = pm[(size_t)(t * BB + b) * NN + j];
      r += w * fast_sigmoid(__fmul_rn(pmi, pmj));
    }
  }
  out[((size_t)b * NN + i) * NN + j] = r * 0.01f;
}

extern "C" void kernel_launch(void* const* d_in, const int* in_sizes, int n_in,
                              void* d_out, int out_size, void* d_ws, size_t ws_size,
                              hipStream_t stream) {
  const float* mu  = (const float*)d_in[0];
  const float* sig = (const float*)d_in[1];
  const float* pi  = (const float*)d_in[2];
  const float* A0  = (const float*)d_in[3];

  char* ws = (char*)d_ws;
  size_t off = 0;
  auto alloc = [&](size_t bytes) -> char* {
    char* p = ws + off;
    off += (bytes + 255) & ~(size_t)255;
    return p;
  };
  float*    llt   = (float*)alloc((size_t)T_STEPS * BB * NN * 4); // 819,200
  float*    ll0   = (float*)alloc(BB * NN * 4);                   // 8,192
  float*    pm    = (float*)alloc((size_t)T_STEPS * BB * NN * 4); // 819,200
  float*    uacc  = (float*)alloc(T_STEPS * 4 * 4);
  int*      slist = (int*)alloc(BB * 104 * 4);
  float*    wlist = (float*)alloc(BB * 104 * 4);
  int*      Mv    = (int*)alloc(4 * 4);
  uint32_t* done  = (uint32_t*)alloc(104 * 4);
  float*    outp  = (float*)d_out;

  hipMemsetAsync(done, 0, 104 * 4, stream);
  fused_kernel<<<1617, 512, 0, stream>>>(mu, sig, pi, A0, pm, uacc, llt, ll0,
                                         done, slist, wlist, Mv);
  out_kernel<<<BB * NN, 512, 0, stream>>>(pm, A0, slist, wlist, Mv, outp);
}

// Round 19
// 146.520 us; speedup vs baseline: 1.2068x; 1.2068x over previous
//
#include <hip/hip_runtime.h>
#include <stdint.h>

#define T_STEPS 100
#define BB 4
#define NN 512
#define KK 10
#define LOG2E 1.4426950408889634

typedef float f4 __attribute__((ext_vector_type(4)));

// ---------------- threefry2x32 (JAX-compatible, 20 rounds) ----------------
__device__ __forceinline__ uint32_t rotl32(uint32_t v, int d) {
  return (v << d) | (v >> (32 - d));
}

__device__ __forceinline__ void tf2x32(uint32_t k0, uint32_t k1,
                                       uint32_t& x0, uint32_t& x1) {
  uint32_t k2 = k0 ^ k1 ^ 0x1BD11BDAu;
  x0 += k0; x1 += k1;
#define TFR(r) { x0 += x1; x1 = rotl32(x1, r); x1 ^= x0; }
  TFR(13) TFR(15) TFR(26) TFR(6)   x0 += k1; x1 += k2 + 1u;
  TFR(17) TFR(29) TFR(16) TFR(24)  x0 += k2; x1 += k0 + 2u;
  TFR(13) TFR(15) TFR(26) TFR(6)   x0 += k0; x1 += k1 + 3u;
  TFR(17) TFR(29) TFR(16) TFR(24)  x0 += k1; x1 += k2 + 4u;
  TFR(13) TFR(15) TFR(26) TFR(6)   x0 += k2; x1 += k0 + 5u;
#undef TFR
}

__device__ __forceinline__ float bits_to_u01(uint32_t bits) {
  return __fsub_rn(__uint_as_float((bits >> 9) | 0x3f800000u), 1.0f);
}

// XLA ErfInv32 (Giles)
__device__ __forceinline__ float erfinv_f32(float x) {
  float w = -logf(__fmul_rn(__fsub_rn(1.0f, x), __fadd_rn(1.0f, x)));
  float p;
  if (w < 5.0f) {
    w = __fsub_rn(w, 2.5f);
    p = 2.81022636e-08f;
    p = __fadd_rn(__fmul_rn(p, w), 3.43273939e-07f);
    p = __fadd_rn(__fmul_rn(p, w), -3.5233877e-06f);
    p = __fadd_rn(__fmul_rn(p, w), -4.39150654e-06f);
    p = __fadd_rn(__fmul_rn(p, w), 0.00021858087f);
    p = __fadd_rn(__fmul_rn(p, w), -0.00125372503f);
    p = __fadd_rn(__fmul_rn(p, w), -0.00417768164f);
    p = __fadd_rn(__fmul_rn(p, w), 0.246640727f);
    p = __fadd_rn(__fmul_rn(p, w), 1.50140941f);
  } else {
    w = __fsub_rn(sqrtf(w), 3.0f);
    p = -0.000200214257f;
    p = __fadd_rn(__fmul_rn(p, w), 0.000100950558f);
    p = __fadd_rn(__fmul_rn(p, w), 0.00134934322f);
    p = __fadd_rn(__fmul_rn(p, w), -0.00367342844f);
    p = __fadd_rn(__fmul_rn(p, w), 0.00573950773f);
    p = __fadd_rn(__fmul_rn(p, w), -0.0076224613f);
    p = __fadd_rn(__fmul_rn(p, w), 0.00943887047f);
    p = __fadd_rn(__fmul_rn(p, w), 1.00167406f);
    p = __fadd_rn(__fmul_rn(p, w), 2.83297682f);
  }
  return __fmul_rn(p, x);
}

// fast sigmoid: 1/(1+exp(-x)) via native exp + native rcp
__device__ __forceinline__ float fast_sigmoid(float x) {
  float e = __expf(-x);
  return __builtin_amdgcn_rcpf(__fadd_rn(1.0f, e));
}

template <int CTRL>
__device__ __forceinline__ float dpp_add(float x) {
  int v = __builtin_amdgcn_update_dpp(0, __float_as_int(x), CTRL, 0xF, 0xF, true);
  return __fadd_rn(x, __int_as_float(v));
}

// ------ Kernel B: RNG + merged prep (per-thread softmax recompute) ----------
__global__ void rng_kernel(const float* __restrict__ mu,
                           const float* __restrict__ sig,
                           const float* __restrict__ pi,
                           float* __restrict__ pm, float* __restrict__ uacc,
                           float* __restrict__ Lf) {
  int id = blockIdx.x * blockDim.x + threadIdx.x;
  if (id >= T_STEPS * BB * NN) return;
  int t = id >> 11;        // /2048
  int m = id & 2047;       // b*512+n

  // --- prep (identical rounding to the verified prep_kernel) ---
  const float* pp = pi + m * KK;
  float mx = pp[0];
  for (int k = 1; k < KK; k++) mx = fmaxf(mx, pp[k]);
  float e[KK]; float s = 0.0f;
  for (int k = 0; k < KK; k++) { e[k] = expf(__fsub_rn(pp[k], mx)); s = __fadd_rn(s, e[k]); }
  float smv = 0.0f, ssv = 0.0f, eps = 0.0f;
  for (int k = 0; k < KK; k++) {
    float p = e[k] / s;
    smv = __fadd_rn(smv, __fmul_rn(p, mu[m * KK + k]));
    ssv = __fadd_rn(ssv, __fmul_rn(p, sig[m * KK + k]));
    eps = __fadd_rn(eps, pp[k]);
  }
  if (t == 0) {
    float ep = fminf(fmaxf(eps, 1e-8f), 1.0f);
    float lep = logf(ep);
    float l1 = logf(__fsub_rn(1.0f, ep));
    Lf[m] = (float)((double)lep - (double)l1);
  }

  // --- partitionable threefry ---
  uint32_t kk0 = 0u, kk1 = (uint32_t)t;
  tf2x32(0u, 42u, kk0, kk1);
  uint32_t n0 = 0u, n1 = 0u; tf2x32(kk0, kk1, n0, n1);   // k_noise
  uint32_t y0 = 0u, y1 = (uint32_t)m;
  tf2x32(n0, n1, y0, y1);
  uint32_t bits = y0 ^ y1;

  float u01 = bits_to_u01(bits);
  const float lo = -0.99999994f;
  float u = fmaxf(lo, __fadd_rn(__fmul_rn(u01, 2.0f), lo));
  float z = __fmul_rn(1.41421356237309515f, erfinv_f32(u));
  pm[id] = __fadd_rn(smv, __fmul_rn(z, ssv));

  if (m < 4) {
    uint32_t u0 = 0u, u1 = 1u; tf2x32(kk0, kk1, u0, u1); // k_unif
    uint32_t c0 = 0u, c1 = (uint32_t)m;
    tf2x32(u0, u1, c0, c1);
    uacc[t * 4 + m] = __fmul_rn(bits_to_u01(c0 ^ c1), 512.0f);  // pre-x512 (exact)
  }
}

// ------ Kernel C: llt (final, log2e-scaled f32) — j-chunk tiling, no combine -
__global__ __launch_bounds__(512) void ll_kernel(const float* __restrict__ pm,
                                                 const float* __restrict__ Lf,
                                                 const float* __restrict__ A0,
                                                 float* __restrict__ llt,
                                                 float* __restrict__ ll0) {
  __shared__ float spm[NN];
  __shared__ float sLc[NN];
  __shared__ double pt[4][128];
  int tid = threadIdx.x;
  int q = tid >> 7, jj = tid & 127;
  int bi = blockIdx.x;
  if (bi < 1600) {
    int tb = bi >> 2, jc = bi & 3;
    int b = tb & 3;
    spm[tid] = pm[tb * NN + tid];
    sLc[tid] = Lf[b * NN + tid];
    __syncthreads();
    int j = jc * 128 + jj;
    float pmj = spm[j];
    int i0 = q * 128;
    double acc = 0.0;
    #pragma unroll 8
    for (int i = 0; i < 128; i += 2) {
      float x0 = __fmul_rn(spm[i0 + i], pmj);
      float x1 = __fmul_rn(spm[i0 + i + 1], pmj);
      float t0 = __fmul_rn(fast_sigmoid(x0), sLc[i0 + i]);
      float t1 = __fmul_rn(fast_sigmoid(x1), sLc[i0 + i + 1]);
      acc += (double)__fadd_rn(t0, t1);
    }
    pt[q][jj] = acc;
    __syncthreads();
    if (tid < 128) {
      double a = ((pt[0][jj] + pt[1][jj]) + pt[2][jj]) + pt[3][jj];
      llt[tb * NN + jc * 128 + jj] = (float)(a * LOG2E);
    }
  } else {
    int idx = bi - 1600;
    int b = idx >> 2, jc = idx & 3;
    sLc[tid] = Lf[b * NN + tid];
    __syncthreads();
    int j = jc * 128 + jj;
    int i0 = q * 128;
    double acc = 0.0;
    #pragma unroll 4
    for (int i = 0; i < 128; i++) {
      acc += (double)A0[(size_t)(i0 + i) * NN + j] * (double)sLc[i0 + i];
    }
    pt[q][jj] = acc;
    __syncthreads();
    if (tid < 128) {
      double a = ((pt[0][jj] + pt[1][jj]) + pt[2][jj]) + pt[3][jj];
      ll0[b * NN + jc * 128 + jj] = (float)(a * LOG2E);
    }
  }
}

// ------- Kernel D: lean f32 single-wave chain ------------------------------
// lane g owns j = k*256 + 4g + c (k=0..1, c=0..3).  Rows pre-scaled by
// log2(e) -> exp is a single v_exp_f32 (exp2f).  Reduce: 4 DPP +
// ds_swizzle(xor16) + ds_bpermute(xor32) == verified ((r0+r1)+(r2+r3)) tree.
// u pre-scaled x512 (exact equivalence with ratio = tot/512).
// History: lane-uniform packed state word -> LDS spk[T] (lane 0 store).
#define CH_LOAD(P, T)                                                        \
  {                                                                          \
    _Pragma("unroll")                                                        \
    for (int b = 0; b < 4; b++) {                                            \
      _Pragma("unroll")                                                      \
      for (int k = 0; k < 2; k++)                                            \
        P[b * 2 + k] = lltv[((size_t)(T) * 4 + b) * 128 + k * 64 + g];       \
    }                                                                        \
  }

#define CH_STEP(P, T)                                                        \
  {                                                                          \
    float4 ua = uaccv[T];                                                    \
    f4 tp0 = (P[0] + P[2]) + (P[4] + P[6]);                                  \
    f4 tp1 = (P[1] + P[3]) + (P[5] + P[7]);                                  \
    f4 d0 = tp0 - S0;                                                        \
    f4 d1 = tp1 - S1;                                                        \
    f4 E0, E1;                                                               \
    _Pragma("unroll")                                                        \
    for (int c = 0; c < 4; c++) {                                            \
      E0[c] = fminf(exp2f(d0[c]), 1.0f);                                     \
      E1[c] = fminf(exp2f(d1[c]), 1.0f);                                     \
    }                                                                        \
    f4 Es = E0 + E1;                                                         \
    float ps = __fadd_rn(__fadd_rn(Es[0], Es[1]), __fadd_rn(Es[2], Es[3]));  \
    ps = dpp_add<0xB1>(ps);   /* xor1 */                                     \
    ps = dpp_add<0x4E>(ps);   /* xor2 */                                     \
    ps = dpp_add<0x141>(ps);  /* xor4 (half-mirror) */                       \
    ps = dpp_add<0x140>(ps);  /* xor8 (mirror) */                            \
    ps = __fadd_rn(ps, __int_as_float(__builtin_amdgcn_ds_swizzle(           \
             __float_as_int(ps), 0x401F)));  /* xor16 */                     \
    ps = __fadd_rn(ps, __int_as_float(__builtin_amdgcn_ds_bpermute(          \
             lx32, __float_as_int(ps))));    /* xor32 */                     \
    if (ua.x < ps) { st0 = (T); cur[0] = P[0]; cur[1] = P[1]; }              \
    if (ua.y < ps) { st1 = (T); cur[2] = P[2]; cur[3] = P[3]; }              \
    if (ua.z < ps) { st2 = (T); cur[4] = P[4]; cur[5] = P[5]; }              \
    if (ua.w < ps) { st3 = (T); cur[6] = P[6]; cur[7] = P[7]; }              \
    S0 = (cur[0] + cur[2]) + (cur[4] + cur[6]);                              \
    S1 = (cur[1] + cur[3]) + (cur[5] + cur[7]);                              \
    if (g == 0) {                                                            \
      uint32_t pk = (uint32_t)(st0 + 1) | ((uint32_t)(st1 + 1) << 8) |       \
                    ((uint32_t)(st2 + 1) << 16) | ((uint32_t)(st3 + 1) << 24);\
      spk[T] = pk;                                                           \
    }                                                                        \
  }

__global__ __launch_bounds__(64, 1) void chain_kernel(const float* __restrict__ llt,
                                                      const float* __restrict__ ll0,
                                                      const float* __restrict__ uacc,
                                                      int* __restrict__ slist,
                                                      float* __restrict__ wlist,
                                                      int* __restrict__ Mv) {
  __shared__ uint32_t spk[T_STEPS];
  __shared__ int scnt[BB][101];
  int g = threadIdx.x;
  int lx32 = (g ^ 32) << 2;

  const f4* lltv = (const f4*)llt;
  const f4* ll0v = (const f4*)ll0;
  const float4* uaccv = (const float4*)uacc;

  f4 cur[8];
  #pragma unroll
  for (int b = 0; b < 4; b++)
    #pragma unroll
    for (int k = 0; k < 2; k++) cur[b * 2 + k] = ll0v[b * 128 + k * 64 + g];
  f4 S0 = (cur[0] + cur[2]) + (cur[4] + cur[6]);
  f4 S1 = (cur[1] + cur[3]) + (cur[5] + cur[7]);
  int st0 = -1, st1 = -1, st2 = -1, st3 = -1;

  f4 Pa[8], Pb[8], Pc[8];
  CH_LOAD(Pa, 0)
  CH_LOAD(Pb, 1)
  CH_LOAD(Pc, 2)

  for (int t = 0; t < 99; t += 3) {
    CH_STEP(Pa, t)
    if (t + 3 < T_STEPS) CH_LOAD(Pa, t + 3)
    CH_STEP(Pb, t + 1)
    if (t + 4 < T_STEPS) CH_LOAD(Pb, t + 4)
    CH_STEP(Pc, t + 2)
    if (t + 5 < T_STEPS) CH_LOAD(Pc, t + 5)
  }
  CH_STEP(Pa, 99)

  // ---- epilogue: histogram + compacted (state, weight) list ----
  __syncthreads();  // single wave: orders spk stores before reads (cheap)
  for (int s = g; s < BB * 101; s += 64) (&scnt[0][0])[s] = 0;
  __syncthreads();
  {
    uint32_t p0 = spk[g];           // step g
    atomicAdd(&scnt[0][p0 & 255], 1);
    atomicAdd(&scnt[1][(p0 >> 8) & 255], 1);
    atomicAdd(&scnt[2][(p0 >> 16) & 255], 1);
    atomicAdd(&scnt[3][p0 >> 24], 1);
    if (g < T_STEPS - 64) {
      uint32_t p1 = spk[64 + g];    // step 64+g
      atomicAdd(&scnt[0][p1 & 255], 1);
      atomicAdd(&scnt[1][(p1 >> 8) & 255], 1);
      atomicAdd(&scnt[2][(p1 >> 16) & 255], 1);
      atomicAdd(&scnt[3][p1 >> 24], 1);
    }
  }
  __syncthreads();
  if (g < 4) {
    int m = 0;
    for (int s = 0; s <= 100; s++) {
      int c = scnt[g][s];
      if (c) { slist[g * 104 + m] = s; wlist[g * 104 + m] = (float)c; m++; }
    }
    Mv[g] = m;
  }
}

// ---------------- Kernel E: out via compacted state list --------------------
__global__ __launch_bounds__(512) void out_kernel(const float* __restrict__ pm,
                                                  const float* __restrict__ A0,
                                                  const int* __restrict__ slist,
                                                  const float* __restrict__ wlist,
                                                  const int* __restrict__ Mv,
                                                  float* __restrict__ out) {
  int b = blockIdx.x >> 9;
  int i = blockIdx.x & 511;
  int j = threadIdx.x;
  int M = Mv[b];
  float r = 0.0f;
  for (int e = 0; e < M; e++) {
    int s = slist[b * 104 + e];
    float w = wlist[b * 104 + e];
    if (s == 0) {
      r += w * A0[(size_t)i * NN + j];
    } else {
      int t = s - 1;
      float pmi = pm[(size_t)(t * BB + b) * NN + i];
      float pmj = pm[(size_t)(t * BB + b) * NN + j];
      r += w * fast_sigmoid(__fmul_rn(pmi, pmj));
    }
  }
  out[((size_t)b * NN + i) * NN + j] = r * 0.01f;
}

extern "C" void kernel_launch(void* const* d_in, const int* in_sizes, int n_in,
                              void* d_out, int out_size, void* d_ws, size_t ws_size,
                              hipStream_t stream) {
  const float* mu  = (const float*)d_in[0];
  const float* sig = (const float*)d_in[1];
  const float* pi  = (const float*)d_in[2];
  const float* A0  = (const float*)d_in[3];

  char* ws = (char*)d_ws;
  size_t off = 0;
  auto alloc = [&](size_t bytes) -> char* {
    char* p = ws + off;
    off += (bytes + 255) & ~(size_t)255;
    return p;
  };
  float* llt   = (float*)alloc((size_t)T_STEPS * BB * NN * 4); // 819,200
  float* ll0   = (float*)alloc(BB * NN * 4);                   // 8,192
  float* pm    = (float*)alloc((size_t)T_STEPS * BB * NN * 4); // 819,200
  float* Lf    = (float*)alloc(BB * NN * 4);
  float* uacc  = (float*)alloc(T_STEPS * 4 * 4);
  int*   slist = (int*)alloc(BB * 104 * 4);
  float* wlist = (float*)alloc(BB * 104 * 4);
  int*   Mv    = (int*)alloc(4 * 4);
  float* outp  = (float*)d_out;

  rng_kernel<<<(T_STEPS * BB * NN + 255) / 256, 256, 0, stream>>>(mu, sig, pi,
                                                                  pm, uacc, Lf);
  ll_kernel<<<1616, 512, 0, stream>>>(pm, Lf, A0, llt, ll0);
  chain_kernel<<<1, 64, 0, stream>>>(llt, ll0, uacc, slist, wlist, Mv);
  out_kernel<<<BB * NN, 512, 0, stream>>>(pm, A0, slist, wlist, Mv, outp);
}